// Round 4
// baseline (1589.181 us; speedup 1.0000x reference)
//
#include <hip/hip_runtime.h>
#include <stdint.h>

#define NN 6144
#define KDIM 6272          // 6144 + 128 (concat K)
#define NB 12288           // 2*NN output cols of big GEMM
#define NTILE 98           // KDIM / 64

typedef __attribute__((ext_vector_type(8))) short bf16x8;
typedef __attribute__((ext_vector_type(4))) float f32x4;

static __device__ __forceinline__ unsigned short f2bf(float f) {
  unsigned u = __float_as_uint(f);
  unsigned r = u + 0x7fffu + ((u >> 16) & 1u);   // RNE to bf16
  return (unsigned short)(r >> 16);
}

// ---------------- zero d_out ----------------
__global__ void zero_kernel(float* __restrict__ p, int n4) {
  int i = blockIdx.x * 256 + threadIdx.x;
  if (i < n4) ((float4*)p)[i] = make_float4(0.f, 0.f, 0.f, 0.f);
}

// ---------------- q/k/v projection (k-chunked, <64KB LDS) ----------------
__global__ __launch_bounds__(256) void qkv_proj(
    const float* __restrict__ h,
    const float* __restrict__ Qw, const float* __restrict__ Qb,
    const float* __restrict__ Kw, const float* __restrict__ Kb,
    const float* __restrict__ Vw, const float* __restrict__ Vb,
    unsigned short* __restrict__ Abf, unsigned short* __restrict__ Bbf,
    unsigned short* __restrict__ vT) {
  __shared__ float Ws[128 * 65];
  __shared__ float hs[64 * 65];
  const int t = threadIdx.x;
  const int r0 = blockIdx.x * 64;
  const int m = blockIdx.y;
  const float* W = (m == 0) ? Qw : (m == 1) ? Kw : Vw;
  const float* bias = (m == 0) ? Qb : (m == 1) ? Kb : Vb;

  const int c = t & 127;
  const int rh = t >> 7;
  float acc[32];
#pragma unroll
  for (int r = 0; r < 32; ++r) acc[r] = 0.f;

  for (int kk = 0; kk < 2; ++kk) {
    __syncthreads();
#pragma unroll
    for (int it = 0; it < 8; ++it) {
      int idx = it * 256 + t;
      int c2 = idx >> 4;
      int q = idx & 15;
      float4 v = ((const float4*)(W + (size_t)c2 * 128 + kk * 64))[q];
      Ws[c2 * 65 + q * 4 + 0] = v.x;
      Ws[c2 * 65 + q * 4 + 1] = v.y;
      Ws[c2 * 65 + q * 4 + 2] = v.z;
      Ws[c2 * 65 + q * 4 + 3] = v.w;
    }
#pragma unroll
    for (int it = 0; it < 4; ++it) {
      int idx = it * 256 + t;
      int r = idx >> 4;
      int q = idx & 15;
      float4 v = ((const float4*)(h + (size_t)(r0 + r) * 128 + kk * 64))[q];
      hs[r * 65 + q * 4 + 0] = v.x;
      hs[r * 65 + q * 4 + 1] = v.y;
      hs[r * 65 + q * 4 + 2] = v.z;
      hs[r * 65 + q * 4 + 3] = v.w;
    }
    __syncthreads();
    for (int k = 0; k < 64; ++k) {
      float wk = Ws[c * 65 + k];
#pragma unroll
      for (int r = 0; r < 32; ++r)
        acc[r] += hs[(rh * 32 + r) * 65 + k] * wk;
    }
  }

  float bv = bias[c];
  float scale = (m == 0) ? 0.08838834764831845f : 1.0f;  // 1/sqrt(128) folded into q
#pragma unroll
  for (int r = 0; r < 32; ++r) {
    int row = r0 + rh * 32 + r;
    unsigned short bf = f2bf((acc[r] + bv) * scale);
    if (m == 0)      Abf[(size_t)row * KDIM + 6144 + c] = bf;
    else if (m == 1) Bbf[(size_t)row * KDIM + 6144 + c] = bf;
    else             vT[(size_t)c * NN + row] = bf;
  }
}

// ---------------- fp32 -> bf16 conversion of e, Pw, Gw ----------------
__global__ __launch_bounds__(256) void convert_kernel(
    const float* __restrict__ e, const float* __restrict__ Pw, const float* __restrict__ Gw,
    unsigned short* __restrict__ Abf, unsigned short* __restrict__ Bbf) {
  const int row = blockIdx.x;
  const int which = blockIdx.y;
  const int t = threadIdx.x;
  const float* src;
  unsigned short* dst;
  if (which == 0)      { src = e  + (size_t)row * NN; dst = Abf + (size_t)row * KDIM; }
  else if (which == 1) { src = Pw + (size_t)row * NN; dst = Bbf + (size_t)row * KDIM; }
  else                 { src = Gw + (size_t)row * NN; dst = Bbf + (size_t)(row + NN) * KDIM; }
#pragma unroll
  for (int it = 0; it < 6; ++it) {
    int j4 = it * 256 + t;
    float4 v = ((const float4*)src)[j4];
    ushort4 p = make_ushort4(f2bf(v.x), f2bf(v.y), f2bf(v.z), f2bf(v.w));
    *(ushort4*)(dst + (size_t)j4 * 4) = p;
  }
  if (which == 2 && t < 32)   // zero the K-pad of the Gw rows
    *(ushort4*)(dst + 6144 + t * 4) = make_ushort4(0, 0, 0, 0);
}

// ---------------- small bf16 NT GEMM (m97 structure, kept for PV) ----------------
template <int ATOMIC>
__global__ __launch_bounds__(256) void gemm_nt(
    const unsigned short* __restrict__ A, const unsigned short* __restrict__ B,
    float* __restrict__ C, int lda, int ldb, int ldc, int kIters) {
  __shared__ short As[128 * 32];
  __shared__ short Bs[128 * 32];
  const int t = threadIdx.x;
  const int wave = t >> 6;
  const int lane = t & 63;
  const int rowBlk = blockIdx.y * 128;
  const int colBlk = blockIdx.x * 128;
  const int kStart = blockIdx.z * kIters * 32;
  const int wm = (wave >> 1) * 64;
  const int wn = (wave & 1) * 64;
  const int lm = lane & 15;
  const int quad = lane >> 4;

  f32x4 acc[4][4] = {};

  const char* Aab = (const char*)A + (size_t)kStart * 2;
  const char* Bab = (const char*)B + (size_t)kStart * 2;
  const size_t ldab = (size_t)lda * 2, ldbb = (size_t)ldb * 2;
  const int o0 = wave * 2048 + lane * 16;

  for (int kb = 0; kb < kIters; ++kb) {
    __syncthreads();
#pragma unroll
    for (int c = 0; c < 2; ++c) {
      int o = o0 + c * 1024;
      int r = o >> 6;
      int cb = o & 63;
      const char* ga = Aab + (size_t)(rowBlk + r) * ldab + (size_t)kb * 64 + cb;
      __builtin_amdgcn_global_load_lds(
          (const __attribute__((address_space(1))) unsigned int*)ga,
          (__attribute__((address_space(3))) unsigned int*)((char*)As + o), 16, 0, 0);
      const char* gb = Bab + (size_t)(colBlk + r) * ldbb + (size_t)kb * 64 + cb;
      __builtin_amdgcn_global_load_lds(
          (const __attribute__((address_space(1))) unsigned int*)gb,
          (__attribute__((address_space(3))) unsigned int*)((char*)Bs + o), 16, 0, 0);
    }
    __syncthreads();

    bf16x8 af[4], bfr[4];
#pragma unroll
    for (int mt = 0; mt < 4; ++mt)
      af[mt] = *(const bf16x8*)&As[(wm + mt * 16 + lm) * 32 + quad * 8];
#pragma unroll
    for (int nt = 0; nt < 4; ++nt)
      bfr[nt] = *(const bf16x8*)&Bs[(wn + nt * 16 + lm) * 32 + quad * 8];
#pragma unroll
    for (int mt = 0; mt < 4; ++mt)
#pragma unroll
      for (int nt = 0; nt < 4; ++nt)
        acc[mt][nt] = __builtin_amdgcn_mfma_f32_16x16x32_bf16(af[mt], bfr[nt], acc[mt][nt], 0, 0, 0);
  }

#pragma unroll
  for (int mt = 0; mt < 4; ++mt)
#pragma unroll
    for (int nt = 0; nt < 4; ++nt) {
      int col = colBlk + wn + nt * 16 + lm;
#pragma unroll
      for (int r = 0; r < 4; ++r) {
        int row = rowBlk + wm + mt * 16 + quad * 4 + r;
        if (ATOMIC) atomicAdd(&C[(size_t)row * ldc + col], acc[mt][nt][r]);
        else        C[(size_t)row * ldc + col] = acc[mt][nt][r];
      }
    }
}

// ---------------- 256x256 8-phase bf16 NT GEMM (m201-style template) ----------------
// BM=BN=256, BK=64, 8 waves (2Mx4N), 512 thr, 128KB LDS.
// Even K-tiles -> buf0, odd -> buf1. Per phase: {1 half-tile stage | ds_reads}
// -> barrier -> setprio(1) -> 16 MFMA -> setprio(0) -> barrier.
// vmcnt(6) only at phases 4/8 (3 half-tiles in flight).
// T2 swizzle: physical unit (row, u) holds logical (row, u ^ (row&7));
// linear LDS dest + pre-swizzled GLOBAL source (rule #21), swizzled ds_read.
// T1: bijective XCD swizzle (1152 % 8 == 0 -> chunk=144): each XCD gets a
// contiguous col-fast run so an A-panel is L2-reused by its 48 col blocks.
#define FENCE() asm volatile("" ::: "memory")
#define BAR() do { FENCE(); __builtin_amdgcn_sched_barrier(0); \
                   __builtin_amdgcn_s_barrier(); \
                   __builtin_amdgcn_sched_barrier(0); FENCE(); } while (0)
#define RDB(buf) do { \
  bR[0][0]=LDB_(buf,0,0); bR[1][0]=LDB_(buf,1,0); bR[2][0]=LDB_(buf,2,0); bR[3][0]=LDB_(buf,3,0); \
  bR[0][1]=LDB_(buf,0,1); bR[1][1]=LDB_(buf,1,1); bR[2][1]=LDB_(buf,2,1); bR[3][1]=LDB_(buf,3,1); } while (0)
#define RDA2(buf,m0,m1) do { \
  aR[m0][0]=LDA_(buf,m0,0); aR[m0][1]=LDA_(buf,m0,1); \
  aR[m1][0]=LDA_(buf,m1,0); aR[m1][1]=LDA_(buf,m1,1); } while (0)
#define MF(m,n,k) acc[m][n]=__builtin_amdgcn_mfma_f32_16x16x32_bf16(aR[m][k],bR[n][k],acc[m][n],0,0,0)
#define MFMA16(m0,m1) do { \
  MF(m0,0,0); MF(m0,1,0); MF(m0,2,0); MF(m0,3,0); \
  MF(m1,0,0); MF(m1,1,0); MF(m1,2,0); MF(m1,3,0); \
  MF(m0,0,1); MF(m0,1,1); MF(m0,2,1); MF(m0,3,1); \
  MF(m1,0,1); MF(m1,1,1); MF(m1,2,1); MF(m1,3,1); } while (0)

__global__ __launch_bounds__(512, 2) void gemm256(
    const unsigned short* __restrict__ A, const unsigned short* __restrict__ B,
    float* __restrict__ C) {
  __shared__ short As[2][256 * 64];
  __shared__ short Bs[2][256 * 64];
  const int t = threadIdx.x;
  const int wave = t >> 6;
  const int lane = t & 63;
  const int wm = wave >> 2;            // 0..1  (M wave row)
  const int wn = wave & 3;             // 0..3  (N wave col)
  const int lm = lane & 15;
  const int quad = lane >> 4;

  // T1 bijective XCD swizzle
  const int nwg = gridDim.x * gridDim.y;                 // 1152, % 8 == 0
  const int orig = blockIdx.y * gridDim.x + blockIdx.x;
  const int chunk = nwg >> 3;
  const int sid = (orig & 7) * chunk + (orig >> 3);
  const int rowBlk = (sid / gridDim.x) * 256;
  const int colBlk = (sid % gridDim.x) * 256;

  const int sRow = wave * 8 + (lane >> 3);                  // staging row in 64-row group
  const int sCol = ((lane & 7) ^ ((lane >> 3) & 7)) * 16;   // pre-swizzled byte col (T2)
  const int sLds = wave * 1024 + lane * 16;                 // linear LDS dest

  f32x4 acc[8][4] = {};
  bf16x8 aR[8][2], bR[4][2];

  auto STAGE = [&](short* lds, const unsigned short* g, int gr0, int tile, int half) {
#pragma unroll
    for (int j = 0; j < 2; ++j) {
      const char* ga = (const char*)g +
          (size_t)(gr0 + half * 128 + j * 64 + sRow) * (size_t)(KDIM * 2) +
          (size_t)tile * 128 + sCol;
      char* la = (char*)lds + half * 16384 + j * 8192 + sLds;
      __builtin_amdgcn_global_load_lds(
          (const __attribute__((address_space(1))) unsigned int*)ga,
          (__attribute__((address_space(3))) unsigned int*)la, 16, 0, 0);
    }
  };
  auto LDA_ = [&](int buf, int mt, int ks) -> bf16x8 {
    int r = wm * 128 + mt * 16 + lm;
    int pc = ((ks * 4 + quad) ^ (lm & 7)) * 16;
    return *(const bf16x8*)((const char*)As[buf] + r * 128 + pc);
  };
  auto LDB_ = [&](int buf, int nt, int ks) -> bf16x8 {
    int r = wn * 64 + nt * 16 + lm;
    int pc = ((ks * 4 + quad) ^ (lm & 7)) * 16;
    return *(const bf16x8*)((const char*)Bs[buf] + r * 128 + pc);
  };

  // prologue: tile0 (A h0,h1, B h0,h1) + tile1 (B h0,h1, A h0) = 7 half-tiles
  STAGE(As[0], A, rowBlk, 0, 0);
  STAGE(As[0], A, rowBlk, 0, 1);
  STAGE(Bs[0], B, colBlk, 0, 0);
  STAGE(Bs[0], B, colBlk, 0, 1);
  STAGE(Bs[1], B, colBlk, 1, 0);
  STAGE(Bs[1], B, colBlk, 1, 1);
  STAGE(As[1], A, rowBlk, 1, 0);
  asm volatile("s_waitcnt vmcnt(6)" ::: "memory");   // tile0 landed
  BAR();

  for (int tk = 0; tk < NTILE; tk += 2) {
    const bool g2 = (tk + 2) < NTILE;
    const bool g3 = (tk + 3) < NTILE;
    // ---- ph1: tile tk (buf0), mt 0,1 ----
    STAGE(As[1], A, rowBlk, tk + 1, 1);              // A h1 of tile tk+1
    RDB(0); RDA2(0, 0, 1);
    asm volatile("s_waitcnt lgkmcnt(8)" ::: "memory");
    BAR();
    __builtin_amdgcn_s_setprio(1); MFMA16(0, 1); __builtin_amdgcn_s_setprio(0);
    BAR();
    // ---- ph2: mt 2,3 ----
    if (g2) STAGE(Bs[0], B, colBlk, tk + 2, 0);
    RDA2(0, 2, 3); RDA2(0, 4, 5);
    BAR();
    __builtin_amdgcn_s_setprio(1); MFMA16(2, 3); __builtin_amdgcn_s_setprio(0);
    BAR();
    // ---- ph3: mt 4,5 ----
    if (g2) STAGE(Bs[0], B, colBlk, tk + 2, 1);
    RDA2(0, 6, 7);
    BAR();
    __builtin_amdgcn_s_setprio(1); MFMA16(4, 5); __builtin_amdgcn_s_setprio(0);
    BAR();
    // ---- ph4: mt 6,7; drain so tile tk+1 is fully present ----
    if (g2) STAGE(As[0], A, rowBlk, tk + 2, 0);
    BAR();
    __builtin_amdgcn_s_setprio(1); MFMA16(6, 7); __builtin_amdgcn_s_setprio(0);
    if (g2) { asm volatile("s_waitcnt vmcnt(6)" ::: "memory"); }
    else    { asm volatile("s_waitcnt vmcnt(0)" ::: "memory"); }
    BAR();
    // ---- ph5: tile tk+1 (buf1), mt 0,1 ----
    if (g2) STAGE(As[0], A, rowBlk, tk + 2, 1);
    RDB(1); RDA2(1, 0, 1);
    asm volatile("s_waitcnt lgkmcnt(8)" ::: "memory");
    BAR();
    __builtin_amdgcn_s_setprio(1); MFMA16(0, 1); __builtin_amdgcn_s_setprio(0);
    BAR();
    // ---- ph6: mt 2,3 ----
    if (g3) STAGE(Bs[1], B, colBlk, tk + 3, 0);
    RDA2(1, 2, 3); RDA2(1, 4, 5);
    BAR();
    __builtin_amdgcn_s_setprio(1); MFMA16(2, 3); __builtin_amdgcn_s_setprio(0);
    BAR();
    // ---- ph7: mt 4,5 ----
    if (g3) STAGE(Bs[1], B, colBlk, tk + 3, 1);
    RDA2(1, 6, 7);
    BAR();
    __builtin_amdgcn_s_setprio(1); MFMA16(4, 5); __builtin_amdgcn_s_setprio(0);
    BAR();
    // ---- ph8: mt 6,7; drain so tile tk+2 is fully present ----
    if (g3) STAGE(As[1], A, rowBlk, tk + 3, 0);
    BAR();
    __builtin_amdgcn_s_setprio(1); MFMA16(6, 7); __builtin_amdgcn_s_setprio(0);
    if (g3) { asm volatile("s_waitcnt vmcnt(6)" ::: "memory"); }
    else    { asm volatile("s_waitcnt vmcnt(0)" ::: "memory"); }
    BAR();
  }

  // ---- C write ----
#pragma unroll
  for (int mt = 0; mt < 8; ++mt)
#pragma unroll
    for (int nt = 0; nt < 4; ++nt) {
      int col = colBlk + wn * 64 + nt * 16 + lm;
#pragma unroll
      for (int r = 0; r < 4; ++r) {
        int row = rowBlk + wm * 128 + mt * 16 + quad * 4 + r;
        C[(size_t)row * NB + col] = acc[mt][nt][r];
      }
    }
}

// ---------------- JAX Threefry-2x32-20, key(42) = (0, 42) ----------------
static __device__ __forceinline__ void threefry(uint32_t& x0, uint32_t& x1) {
  const uint32_t ks0 = 0u, ks1 = 42u, ks2 = 0u ^ 42u ^ 0x1BD11BDAu;
  x0 += ks0; x1 += ks1;
#define TFR(r) { x0 += x1; x1 = (x1 << (r)) | (x1 >> (32 - (r))); x1 ^= x0; }
  TFR(13) TFR(15) TFR(26) TFR(6)
  x0 += ks1; x1 += ks2 + 1u;
  TFR(17) TFR(29) TFR(16) TFR(24)
  x0 += ks2; x1 += ks0 + 2u;
  TFR(13) TFR(15) TFR(26) TFR(6)
  x0 += ks0; x1 += ks1 + 3u;
  TFR(17) TFR(29) TFR(16) TFR(24)
  x0 += ks1; x1 += ks2 + 4u;
  TFR(13) TFR(15) TFR(26) TFR(6)
  x0 += ks2; x1 += ks0 + 5u;
#undef TFR
}

// Partitionable threefry (JAX default), x32 mode: counter (0, i);
// bits = y0 ^ y1; u = bitcast((bits>>9)|0x3F800000) - 1.0f; keep = u < 0.8f
static __device__ __forceinline__ int keep32p(uint32_t idx) {
  uint32_t x0 = 0u, x1 = idx;
  threefry(x0, x1);
  uint32_t bits = x0 ^ x1;
  float u = __uint_as_float((bits >> 9) | 0x3F800000u) - 1.0f;
  return u < 0.8f;
}

// ---------------- softmax + bias + sigmoid-gate + dropout ----------------
__global__ __launch_bounds__(256) void softmax_gate(
    const float* __restrict__ C,
    const float* __restrict__ Pb, const float* __restrict__ Gb,
    unsigned short* __restrict__ attw) {
  __shared__ float srow[NN];
  __shared__ float red[4];
  const int t = threadIdx.x;
  const int wave = t >> 6, lane = t & 63;
  const int i = blockIdx.x;

  float mx = -1e30f;
  const float4* src = (const float4*)(C + (size_t)i * NB);
  const float4* pb4 = (const float4*)Pb;
#pragma unroll
  for (int it = 0; it < 6; ++it) {
    int j4 = it * 256 + t;
    float4 v = src[j4];
    float4 p = pb4[j4];
    v.x += p.x; v.y += p.y; v.z += p.z; v.w += p.w;
    ((float4*)srow)[j4] = v;
    mx = fmaxf(mx, fmaxf(fmaxf(v.x, v.y), fmaxf(v.z, v.w)));
  }
  for (int off = 32; off > 0; off >>= 1) mx = fmaxf(mx, __shfl_xor(mx, off, 64));
  if (lane == 0) red[wave] = mx;
  __syncthreads();
  const float M = fmaxf(fmaxf(red[0], red[1]), fmaxf(red[2], red[3]));
  __syncthreads();

  float sm = 0.f;
#pragma unroll
  for (int it = 0; it < 6; ++it) {
    int j4 = it * 256 + t;
    float4 v = ((float4*)srow)[j4];
    v.x = __expf(v.x - M); v.y = __expf(v.y - M);
    v.z = __expf(v.z - M); v.w = __expf(v.w - M);
    ((float4*)srow)[j4] = v;
    sm += v.x + v.y + v.z + v.w;
  }
  for (int off = 32; off > 0; off >>= 1) sm += __shfl_xor(sm, off, 64);
  if (lane == 0) red[wave] = sm;
  __syncthreads();
  const float inv = 1.25f / (red[0] + red[1] + red[2] + red[3]);  // 1/(0.8*sum)

  const float4* gp  = (const float4*)(C + (size_t)i * NB + 6144);
  const float4* gb4 = (const float4*)Gb;
  const uint32_t base = (uint32_t)i * (uint32_t)NN;
  for (int it = 0; it < 6; ++it) {
    int j4 = it * 256 + t;
    int j = j4 * 4;
    float4 gl = gp[j4], gb = gb4[j4];
    float4 pv = ((float4*)srow)[j4];
    float a[4] = { gl.x, gl.y, gl.z, gl.w };
    float ab[4] = { gb.x, gb.y, gb.z, gb.w };
    float ev[4] = { pv.x, pv.y, pv.z, pv.w };
    unsigned short w[4];
#pragma unroll
    for (int u = 0; u < 4; ++u) {
      int kp = keep32p(base + (uint32_t)(j + u));
      float s = 1.f / (1.f + __expf(-(a[u] + ab[u])));
      float val = kp ? s * ev[u] * inv : 0.f;
      w[u] = f2bf(val);
    }
    *(ushort4*)(attw + (size_t)i * NN + j) = make_ushort4(w[0], w[1], w[2], w[3]);
  }
}

// ---------------- launch ----------------
extern "C" void kernel_launch(void* const* d_in, const int* in_sizes, int n_in,
                              void* d_out, int out_size, void* d_ws, size_t ws_size,
                              hipStream_t stream) {
  (void)in_sizes; (void)n_in; (void)out_size; (void)ws_size;
  const float* h  = (const float*)d_in[0];
  const float* e  = (const float*)d_in[1];
  const float* Qw = (const float*)d_in[2];
  const float* Qb = (const float*)d_in[3];
  const float* Kw = (const float*)d_in[4];
  const float* Kb = (const float*)d_in[5];
  const float* Vw = (const float*)d_in[6];
  const float* Vb = (const float*)d_in[7];
  const float* Pw = (const float*)d_in[8];
  const float* Pb = (const float*)d_in[9];
  const float* Gw = (const float*)d_in[10];
  const float* Gb = (const float*)d_in[11];
  float* out = (float*)d_out;

  char* ws = (char*)d_ws;
  unsigned short* Abf  = (unsigned short*)(ws);                       // [6144][6272] bf16: [e | q/sqrt(d)]
  unsigned short* Bbf  = (unsigned short*)(ws + 77070336ull);         // [12288][6272] bf16: [[Pw|k],[Gw|0]]
  float*          Cbuf = (float*)(ws + 231211008ull);                 // [6144][12288] fp32
  unsigned short* vT   = (unsigned short*)(ws + 533348352ull);        // [128][6144] bf16
  unsigned short* attw = Abf;  // alias: A' dead after big GEMM

  zero_kernel<<<768, 256, 0, stream>>>(out, 196608);
  qkv_proj<<<dim3(96, 3), 256, 0, stream>>>(h, Qw, Qb, Kw, Kb, Vw, Vb, Abf, Bbf, vT);
  convert_kernel<<<dim3(6144, 3), 256, 0, stream>>>(e, Pw, Gw, Abf, Bbf);
  gemm256<<<dim3(48, 24), 512, 0, stream>>>(Abf, Bbf, Cbuf);
  softmax_gate<<<6144, 256, 0, stream>>>(Cbuf, Pb, Gb, attw);
  gemm_nt<1><<<dim3(1, 48, 12), 256, 0, stream>>>(attw, vT, out, NN, NN, 128, 16);
}

// Round 5
// 1554.260 us; speedup vs baseline: 1.0225x; 1.0225x over previous
//
#include <hip/hip_runtime.h>
#include <stdint.h>

#define NN 6144
#define KDIM 6272          // 6144 + 128 (concat K)
#define NB 12288           // 2*NN output cols of big GEMM
#define NTILE 98           // KDIM / 64

typedef __attribute__((ext_vector_type(8))) short bf16x8;
typedef __attribute__((ext_vector_type(4))) float f32x4;

static __device__ __forceinline__ unsigned short f2bf(float f) {
  unsigned u = __float_as_uint(f);
  unsigned r = u + 0x7fffu + ((u >> 16) & 1u);   // RNE to bf16
  return (unsigned short)(r >> 16);
}

// ---------------- zero d_out ----------------
__global__ void zero_kernel(float* __restrict__ p, int n4) {
  int i = blockIdx.x * 256 + threadIdx.x;
  if (i < n4) ((float4*)p)[i] = make_float4(0.f, 0.f, 0.f, 0.f);
}

// ---------------- q/k/v projection (k-chunked, <64KB LDS) ----------------
__global__ __launch_bounds__(256) void qkv_proj(
    const float* __restrict__ h,
    const float* __restrict__ Qw, const float* __restrict__ Qb,
    const float* __restrict__ Kw, const float* __restrict__ Kb,
    const float* __restrict__ Vw, const float* __restrict__ Vb,
    unsigned short* __restrict__ Abf, unsigned short* __restrict__ Bbf,
    unsigned short* __restrict__ vT) {
  __shared__ float Ws[128 * 65];
  __shared__ float hs[64 * 65];
  const int t = threadIdx.x;
  const int r0 = blockIdx.x * 64;
  const int m = blockIdx.y;
  const float* W = (m == 0) ? Qw : (m == 1) ? Kw : Vw;
  const float* bias = (m == 0) ? Qb : (m == 1) ? Kb : Vb;

  const int c = t & 127;
  const int rh = t >> 7;
  float acc[32];
#pragma unroll
  for (int r = 0; r < 32; ++r) acc[r] = 0.f;

  for (int kk = 0; kk < 2; ++kk) {
    __syncthreads();
#pragma unroll
    for (int it = 0; it < 8; ++it) {
      int idx = it * 256 + t;
      int c2 = idx >> 4;
      int q = idx & 15;
      float4 v = ((const float4*)(W + (size_t)c2 * 128 + kk * 64))[q];
      Ws[c2 * 65 + q * 4 + 0] = v.x;
      Ws[c2 * 65 + q * 4 + 1] = v.y;
      Ws[c2 * 65 + q * 4 + 2] = v.z;
      Ws[c2 * 65 + q * 4 + 3] = v.w;
    }
#pragma unroll
    for (int it = 0; it < 4; ++it) {
      int idx = it * 256 + t;
      int r = idx >> 4;
      int q = idx & 15;
      float4 v = ((const float4*)(h + (size_t)(r0 + r) * 128 + kk * 64))[q];
      hs[r * 65 + q * 4 + 0] = v.x;
      hs[r * 65 + q * 4 + 1] = v.y;
      hs[r * 65 + q * 4 + 2] = v.z;
      hs[r * 65 + q * 4 + 3] = v.w;
    }
    __syncthreads();
    for (int k = 0; k < 64; ++k) {
      float wk = Ws[c * 65 + k];
#pragma unroll
      for (int r = 0; r < 32; ++r)
        acc[r] += hs[(rh * 32 + r) * 65 + k] * wk;
    }
  }

  float bv = bias[c];
  float scale = (m == 0) ? 0.08838834764831845f : 1.0f;  // 1/sqrt(128) folded into q
#pragma unroll
  for (int r = 0; r < 32; ++r) {
    int row = r0 + rh * 32 + r;
    unsigned short bf = f2bf((acc[r] + bv) * scale);
    if (m == 0)      Abf[(size_t)row * KDIM + 6144 + c] = bf;
    else if (m == 1) Bbf[(size_t)row * KDIM + 6144 + c] = bf;
    else             vT[(size_t)c * NN + row] = bf;
  }
}

// ---------------- fp32 -> bf16 conversion of e, Pw, Gw ----------------
__global__ __launch_bounds__(256) void convert_kernel(
    const float* __restrict__ e, const float* __restrict__ Pw, const float* __restrict__ Gw,
    unsigned short* __restrict__ Abf, unsigned short* __restrict__ Bbf) {
  const int row = blockIdx.x;
  const int which = blockIdx.y;
  const int t = threadIdx.x;
  const float* src;
  unsigned short* dst;
  if (which == 0)      { src = e  + (size_t)row * NN; dst = Abf + (size_t)row * KDIM; }
  else if (which == 1) { src = Pw + (size_t)row * NN; dst = Bbf + (size_t)row * KDIM; }
  else                 { src = Gw + (size_t)row * NN; dst = Bbf + (size_t)(row + NN) * KDIM; }
#pragma unroll
  for (int it = 0; it < 6; ++it) {
    int j4 = it * 256 + t;
    float4 v = ((const float4*)src)[j4];
    ushort4 p = make_ushort4(f2bf(v.x), f2bf(v.y), f2bf(v.z), f2bf(v.w));
    *(ushort4*)(dst + (size_t)j4 * 4) = p;
  }
  if (which == 2 && t < 32)   // zero the K-pad of the Gw rows
    *(ushort4*)(dst + 6144 + t * 4) = make_ushort4(0, 0, 0, 0);
}

// ---------------- small bf16 NT GEMM (m97 structure, kept for PV) ----------------
template <int ATOMIC>
__global__ __launch_bounds__(256) void gemm_nt(
    const unsigned short* __restrict__ A, const unsigned short* __restrict__ B,
    float* __restrict__ C, int lda, int ldb, int ldc, int kIters) {
  __shared__ short As[128 * 32];
  __shared__ short Bs[128 * 32];
  const int t = threadIdx.x;
  const int wave = t >> 6;
  const int lane = t & 63;
  const int rowBlk = blockIdx.y * 128;
  const int colBlk = blockIdx.x * 128;
  const int kStart = blockIdx.z * kIters * 32;
  const int wm = (wave >> 1) * 64;
  const int wn = (wave & 1) * 64;
  const int lm = lane & 15;
  const int quad = lane >> 4;

  f32x4 acc[4][4] = {};

  const char* Aab = (const char*)A + (size_t)kStart * 2;
  const char* Bab = (const char*)B + (size_t)kStart * 2;
  const size_t ldab = (size_t)lda * 2, ldbb = (size_t)ldb * 2;
  const int o0 = wave * 2048 + lane * 16;

  for (int kb = 0; kb < kIters; ++kb) {
    __syncthreads();
#pragma unroll
    for (int c = 0; c < 2; ++c) {
      int o = o0 + c * 1024;
      int r = o >> 6;
      int cb = o & 63;
      const char* ga = Aab + (size_t)(rowBlk + r) * ldab + (size_t)kb * 64 + cb;
      __builtin_amdgcn_global_load_lds(
          (const __attribute__((address_space(1))) unsigned int*)ga,
          (__attribute__((address_space(3))) unsigned int*)((char*)As + o), 16, 0, 0);
      const char* gb = Bab + (size_t)(colBlk + r) * ldbb + (size_t)kb * 64 + cb;
      __builtin_amdgcn_global_load_lds(
          (const __attribute__((address_space(1))) unsigned int*)gb,
          (__attribute__((address_space(3))) unsigned int*)((char*)Bs + o), 16, 0, 0);
    }
    __syncthreads();

    bf16x8 af[4], bfr[4];
#pragma unroll
    for (int mt = 0; mt < 4; ++mt)
      af[mt] = *(const bf16x8*)&As[(wm + mt * 16 + lm) * 32 + quad * 8];
#pragma unroll
    for (int nt = 0; nt < 4; ++nt)
      bfr[nt] = *(const bf16x8*)&Bs[(wn + nt * 16 + lm) * 32 + quad * 8];
#pragma unroll
    for (int mt = 0; mt < 4; ++mt)
#pragma unroll
      for (int nt = 0; nt < 4; ++nt)
        acc[mt][nt] = __builtin_amdgcn_mfma_f32_16x16x32_bf16(af[mt], bfr[nt], acc[mt][nt], 0, 0, 0);
  }

#pragma unroll
  for (int mt = 0; mt < 4; ++mt)
#pragma unroll
    for (int nt = 0; nt < 4; ++nt) {
      int col = colBlk + wn + nt * 16 + lm;
#pragma unroll
      for (int r = 0; r < 4; ++r) {
        int row = rowBlk + wm + mt * 16 + quad * 4 + r;
        if (ATOMIC) atomicAdd(&C[(size_t)row * ldc + col], acc[mt][nt][r]);
        else        C[(size_t)row * ldc + col] = acc[mt][nt][r];
      }
    }
}

// ---------------- 256x256 8-phase bf16 NT GEMM (m201-style template) ----------------
// BM=BN=256, BK=64, 8 waves (2Mx4N), 512 thr, 128KB LDS.
// Even K-tiles -> buf0, odd -> buf1. Per phase: {1 half-tile stage | ds_reads}
// -> barrier -> setprio(1) -> 16 MFMA -> setprio(0) -> barrier.
// vmcnt(6) only at phases 4/8 (3 half-tiles in flight).
// T2 swizzle: physical unit (row, u) holds logical (row, u ^ (row&7));
// linear LDS dest + pre-swizzled GLOBAL source (rule #21), swizzled ds_read.
// NOTE: XCD swizzle (round 4) REVERTED — it doubled FETCH_SIZE (856MB->1.89GB)
// and cost 3%: the real workgroup->XCD dispatch anti-correlates with the %8
// assumption on this grid. Default x-fast order keeps a row-band working set
// that is L3-resident.
#define FENCE() asm volatile("" ::: "memory")
#define BAR() do { FENCE(); __builtin_amdgcn_sched_barrier(0); \
                   __builtin_amdgcn_s_barrier(); \
                   __builtin_amdgcn_sched_barrier(0); FENCE(); } while (0)
#define RDB(buf) do { \
  bR[0][0]=LDB_(buf,0,0); bR[1][0]=LDB_(buf,1,0); bR[2][0]=LDB_(buf,2,0); bR[3][0]=LDB_(buf,3,0); \
  bR[0][1]=LDB_(buf,0,1); bR[1][1]=LDB_(buf,1,1); bR[2][1]=LDB_(buf,2,1); bR[3][1]=LDB_(buf,3,1); } while (0)
#define RDA2(buf,m0,m1) do { \
  aR[m0][0]=LDA_(buf,m0,0); aR[m0][1]=LDA_(buf,m0,1); \
  aR[m1][0]=LDA_(buf,m1,0); aR[m1][1]=LDA_(buf,m1,1); } while (0)
#define MF(m,n,k) acc[m][n]=__builtin_amdgcn_mfma_f32_16x16x32_bf16(aR[m][k],bR[n][k],acc[m][n],0,0,0)
#define MFMA16(m0,m1) do { \
  MF(m0,0,0); MF(m0,1,0); MF(m0,2,0); MF(m0,3,0); \
  MF(m1,0,0); MF(m1,1,0); MF(m1,2,0); MF(m1,3,0); \
  MF(m0,0,1); MF(m0,1,1); MF(m0,2,1); MF(m0,3,1); \
  MF(m1,0,1); MF(m1,1,1); MF(m1,2,1); MF(m1,3,1); } while (0)

__global__ __launch_bounds__(512, 2) void gemm256(
    const unsigned short* __restrict__ A, const unsigned short* __restrict__ B,
    float* __restrict__ C) {
  __shared__ short As[2][256 * 64];
  __shared__ short Bs[2][256 * 64];
  const int t = threadIdx.x;
  const int wave = t >> 6;
  const int lane = t & 63;
  const int wm = wave >> 2;            // 0..1  (M wave row)
  const int wn = wave & 3;             // 0..3  (N wave col)
  const int lm = lane & 15;
  const int quad = lane >> 4;
  const int rowBlk = blockIdx.y * 256;
  const int colBlk = blockIdx.x * 256;

  const int sRow = wave * 8 + (lane >> 3);                  // staging row in 64-row group
  const int sCol = ((lane & 7) ^ ((lane >> 3) & 7)) * 16;   // pre-swizzled byte col (T2)
  const int sLds = wave * 1024 + lane * 16;                 // linear LDS dest

  f32x4 acc[8][4] = {};
  bf16x8 aR[8][2], bR[4][2];

  auto STAGE = [&](short* lds, const unsigned short* g, int gr0, int tile, int half) {
#pragma unroll
    for (int j = 0; j < 2; ++j) {
      const char* ga = (const char*)g +
          (size_t)(gr0 + half * 128 + j * 64 + sRow) * (size_t)(KDIM * 2) +
          (size_t)tile * 128 + sCol;
      char* la = (char*)lds + half * 16384 + j * 8192 + sLds;
      __builtin_amdgcn_global_load_lds(
          (const __attribute__((address_space(1))) unsigned int*)ga,
          (__attribute__((address_space(3))) unsigned int*)la, 16, 0, 0);
    }
  };
  auto LDA_ = [&](int buf, int mt, int ks) -> bf16x8 {
    int r = wm * 128 + mt * 16 + lm;
    int pc = ((ks * 4 + quad) ^ (lm & 7)) * 16;
    return *(const bf16x8*)((const char*)As[buf] + r * 128 + pc);
  };
  auto LDB_ = [&](int buf, int nt, int ks) -> bf16x8 {
    int r = wn * 64 + nt * 16 + lm;
    int pc = ((ks * 4 + quad) ^ (lm & 7)) * 16;
    return *(const bf16x8*)((const char*)Bs[buf] + r * 128 + pc);
  };

  // prologue: tile0 (A h0,h1, B h0,h1) + tile1 (B h0,h1, A h0) = 7 half-tiles
  STAGE(As[0], A, rowBlk, 0, 0);
  STAGE(As[0], A, rowBlk, 0, 1);
  STAGE(Bs[0], B, colBlk, 0, 0);
  STAGE(Bs[0], B, colBlk, 0, 1);
  STAGE(Bs[1], B, colBlk, 1, 0);
  STAGE(Bs[1], B, colBlk, 1, 1);
  STAGE(As[1], A, rowBlk, 1, 0);
  asm volatile("s_waitcnt vmcnt(6)" ::: "memory");   // tile0 landed
  BAR();

  for (int tk = 0; tk < NTILE; tk += 2) {
    const bool g2 = (tk + 2) < NTILE;
    const bool g3 = (tk + 3) < NTILE;
    // ---- ph1: tile tk (buf0), mt 0,1 ----
    STAGE(As[1], A, rowBlk, tk + 1, 1);              // A h1 of tile tk+1
    RDB(0); RDA2(0, 0, 1);
    asm volatile("s_waitcnt lgkmcnt(8)" ::: "memory");
    BAR();
    __builtin_amdgcn_s_setprio(1); MFMA16(0, 1); __builtin_amdgcn_s_setprio(0);
    BAR();
    // ---- ph2: mt 2,3 ----
    if (g2) STAGE(Bs[0], B, colBlk, tk + 2, 0);
    RDA2(0, 2, 3); RDA2(0, 4, 5);
    BAR();
    __builtin_amdgcn_s_setprio(1); MFMA16(2, 3); __builtin_amdgcn_s_setprio(0);
    BAR();
    // ---- ph3: mt 4,5 ----
    if (g2) STAGE(Bs[0], B, colBlk, tk + 2, 1);
    RDA2(0, 6, 7);
    BAR();
    __builtin_amdgcn_s_setprio(1); MFMA16(4, 5); __builtin_amdgcn_s_setprio(0);
    BAR();
    // ---- ph4: mt 6,7; drain so tile tk+1 is fully present ----
    if (g2) STAGE(As[0], A, rowBlk, tk + 2, 0);
    BAR();
    __builtin_amdgcn_s_setprio(1); MFMA16(6, 7); __builtin_amdgcn_s_setprio(0);
    if (g2) { asm volatile("s_waitcnt vmcnt(6)" ::: "memory"); }
    else    { asm volatile("s_waitcnt vmcnt(0)" ::: "memory"); }
    BAR();
    // ---- ph5: tile tk+1 (buf1), mt 0,1 ----
    if (g2) STAGE(As[0], A, rowBlk, tk + 2, 1);
    RDB(1); RDA2(1, 0, 1);
    asm volatile("s_waitcnt lgkmcnt(8)" ::: "memory");
    BAR();
    __builtin_amdgcn_s_setprio(1); MFMA16(0, 1); __builtin_amdgcn_s_setprio(0);
    BAR();
    // ---- ph6: mt 2,3 ----
    if (g3) STAGE(Bs[1], B, colBlk, tk + 3, 0);
    RDA2(1, 2, 3); RDA2(1, 4, 5);
    BAR();
    __builtin_amdgcn_s_setprio(1); MFMA16(2, 3); __builtin_amdgcn_s_setprio(0);
    BAR();
    // ---- ph7: mt 4,5 ----
    if (g3) STAGE(Bs[1], B, colBlk, tk + 3, 1);
    RDA2(1, 6, 7);
    BAR();
    __builtin_amdgcn_s_setprio(1); MFMA16(4, 5); __builtin_amdgcn_s_setprio(0);
    BAR();
    // ---- ph8: mt 6,7; drain so tile tk+2 is fully present ----
    if (g3) STAGE(As[1], A, rowBlk, tk + 3, 0);
    BAR();
    __builtin_amdgcn_s_setprio(1); MFMA16(6, 7); __builtin_amdgcn_s_setprio(0);
    if (g3) { asm volatile("s_waitcnt vmcnt(6)" ::: "memory"); }
    else    { asm volatile("s_waitcnt vmcnt(0)" ::: "memory"); }
    BAR();
  }

  // ---- C write ----
#pragma unroll
  for (int mt = 0; mt < 8; ++mt)
#pragma unroll
    for (int nt = 0; nt < 4; ++nt) {
      int col = colBlk + wn * 64 + nt * 16 + lm;
#pragma unroll
      for (int r = 0; r < 4; ++r) {
        int row = rowBlk + wm * 128 + mt * 16 + quad * 4 + r;
        C[(size_t)row * NB + col] = acc[mt][nt][r];
      }
    }
}

// ---------------- JAX Threefry-2x32-20, key(42) = (0, 42) ----------------
static __device__ __forceinline__ void threefry(uint32_t& x0, uint32_t& x1) {
  const uint32_t ks0 = 0u, ks1 = 42u, ks2 = 0u ^ 42u ^ 0x1BD11BDAu;
  x0 += ks0; x1 += ks1;
#define TFR(r) { x0 += x1; x1 = (x1 << (r)) | (x1 >> (32 - (r))); x1 ^= x0; }
  TFR(13) TFR(15) TFR(26) TFR(6)
  x0 += ks1; x1 += ks2 + 1u;
  TFR(17) TFR(29) TFR(16) TFR(24)
  x0 += ks2; x1 += ks0 + 2u;
  TFR(13) TFR(15) TFR(26) TFR(6)
  x0 += ks0; x1 += ks1 + 3u;
  TFR(17) TFR(29) TFR(16) TFR(24)
  x0 += ks1; x1 += ks2 + 4u;
  TFR(13) TFR(15) TFR(26) TFR(6)
  x0 += ks2; x1 += ks0 + 5u;
#undef TFR
}

// Partitionable threefry (JAX default), x32 mode: counter (0, i);
// bits = y0 ^ y1; u = bitcast((bits>>9)|0x3F800000) - 1.0f; keep = u < 0.8f
static __device__ __forceinline__ int keep32p(uint32_t idx) {
  uint32_t x0 = 0u, x1 = idx;
  threefry(x0, x1);
  uint32_t bits = x0 ^ x1;
  float u = __uint_as_float((bits >> 9) | 0x3F800000u) - 1.0f;
  return u < 0.8f;
}

// ---------------- softmax + bias + sigmoid-gate + dropout ----------------
__global__ __launch_bounds__(256) void softmax_gate(
    const float* __restrict__ C,
    const float* __restrict__ Pb, const float* __restrict__ Gb,
    unsigned short* __restrict__ attw) {
  __shared__ float srow[NN];
  __shared__ float red[4];
  const int t = threadIdx.x;
  const int wave = t >> 6, lane = t & 63;
  const int i = blockIdx.x;

  float mx = -1e30f;
  const float4* src = (const float4*)(C + (size_t)i * NB);
  const float4* pb4 = (const float4*)Pb;
#pragma unroll
  for (int it = 0; it < 6; ++it) {
    int j4 = it * 256 + t;
    float4 v = src[j4];
    float4 p = pb4[j4];
    v.x += p.x; v.y += p.y; v.z += p.z; v.w += p.w;
    ((float4*)srow)[j4] = v;
    mx = fmaxf(mx, fmaxf(fmaxf(v.x, v.y), fmaxf(v.z, v.w)));
  }
  for (int off = 32; off > 0; off >>= 1) mx = fmaxf(mx, __shfl_xor(mx, off, 64));
  if (lane == 0) red[wave] = mx;
  __syncthreads();
  const float M = fmaxf(fmaxf(red[0], red[1]), fmaxf(red[2], red[3]));
  __syncthreads();

  float sm = 0.f;
#pragma unroll
  for (int it = 0; it < 6; ++it) {
    int j4 = it * 256 + t;
    float4 v = ((float4*)srow)[j4];
    v.x = __expf(v.x - M); v.y = __expf(v.y - M);
    v.z = __expf(v.z - M); v.w = __expf(v.w - M);
    ((float4*)srow)[j4] = v;
    sm += v.x + v.y + v.z + v.w;
  }
  for (int off = 32; off > 0; off >>= 1) sm += __shfl_xor(sm, off, 64);
  if (lane == 0) red[wave] = sm;
  __syncthreads();
  const float inv = 1.25f / (red[0] + red[1] + red[2] + red[3]);  // 1/(0.8*sum)

  const float4* gp  = (const float4*)(C + (size_t)i * NB + 6144);
  const float4* gb4 = (const float4*)Gb;
  const uint32_t base = (uint32_t)i * (uint32_t)NN;
  for (int it = 0; it < 6; ++it) {
    int j4 = it * 256 + t;
    int j = j4 * 4;
    float4 gl = gp[j4], gb = gb4[j4];
    float4 pv = ((float4*)srow)[j4];
    float a[4] = { gl.x, gl.y, gl.z, gl.w };
    float ab[4] = { gb.x, gb.y, gb.z, gb.w };
    float ev[4] = { pv.x, pv.y, pv.z, pv.w };
    unsigned short w[4];
#pragma unroll
    for (int u = 0; u < 4; ++u) {
      int kp = keep32p(base + (uint32_t)(j + u));
      float s = 1.f / (1.f + __expf(-(a[u] + ab[u])));
      float val = kp ? s * ev[u] * inv : 0.f;
      w[u] = f2bf(val);
    }
    *(ushort4*)(attw + (size_t)i * NN + j) = make_ushort4(w[0], w[1], w[2], w[3]);
  }
}

// ---------------- launch ----------------
extern "C" void kernel_launch(void* const* d_in, const int* in_sizes, int n_in,
                              void* d_out, int out_size, void* d_ws, size_t ws_size,
                              hipStream_t stream) {
  (void)in_sizes; (void)n_in; (void)out_size; (void)ws_size;
  const float* h  = (const float*)d_in[0];
  const float* e  = (const float*)d_in[1];
  const float* Qw = (const float*)d_in[2];
  const float* Qb = (const float*)d_in[3];
  const float* Kw = (const float*)d_in[4];
  const float* Kb = (const float*)d_in[5];
  const float* Vw = (const float*)d_in[6];
  const float* Vb = (const float*)d_in[7];
  const float* Pw = (const float*)d_in[8];
  const float* Pb = (const float*)d_in[9];
  const float* Gw = (const float*)d_in[10];
  const float* Gb = (const float*)d_in[11];
  float* out = (float*)d_out;

  char* ws = (char*)d_ws;
  unsigned short* Abf  = (unsigned short*)(ws);                       // [6144][6272] bf16: [e | q/sqrt(d)]
  unsigned short* Bbf  = (unsigned short*)(ws + 77070336ull);         // [12288][6272] bf16: [[Pw|k],[Gw|0]]
  float*          Cbuf = (float*)(ws + 231211008ull);                 // [6144][12288] fp32
  unsigned short* vT   = (unsigned short*)(ws + 533348352ull);        // [128][6144] bf16
  unsigned short* attw = Abf;  // alias: A' dead after big GEMM

  zero_kernel<<<768, 256, 0, stream>>>(out, 196608);
  qkv_proj<<<dim3(96, 3), 256, 0, stream>>>(h, Qw, Qb, Kw, Kb, Vw, Vb, Abf, Bbf, vT);
  convert_kernel<<<dim3(6144, 3), 256, 0, stream>>>(e, Pw, Gw, Abf, Bbf);
  gemm256<<<dim3(48, 24), 512, 0, stream>>>(Abf, Bbf, Cbuf);
  softmax_gate<<<6144, 256, 0, stream>>>(Cbuf, Pb, Gb, attw);
  gemm_nt<1><<<dim3(1, 48, 12), 256, 0, stream>>>(attw, vT, out, NN, NN, 128, 16);
}

// Round 6
// 1527.614 us; speedup vs baseline: 1.0403x; 1.0174x over previous
//
#include <hip/hip_runtime.h>
#include <stdint.h>

#define NN 6144
#define KDIM 6272          // 6144 + 128 (concat K)
#define NB 12288           // 2*NN output cols of big GEMM
#define NTILE 98           // KDIM / 64

typedef __attribute__((ext_vector_type(8))) short bf16x8;
typedef __attribute__((ext_vector_type(4))) float f32x4;

static __device__ __forceinline__ unsigned short f2bf(float f) {
  unsigned u = __float_as_uint(f);
  unsigned r = u + 0x7fffu + ((u >> 16) & 1u);   // RNE to bf16
  return (unsigned short)(r >> 16);
}
static __device__ __forceinline__ float bf2f(unsigned short u) {
  return __uint_as_float(((unsigned)u) << 16);
}

// ---------------- zero d_out ----------------
__global__ void zero_kernel(float* __restrict__ p, int n4) {
  int i = blockIdx.x * 256 + threadIdx.x;
  if (i < n4) ((float4*)p)[i] = make_float4(0.f, 0.f, 0.f, 0.f);
}

// ---------------- q/k/v projection (k-chunked, <64KB LDS) ----------------
__global__ __launch_bounds__(256) void qkv_proj(
    const float* __restrict__ h,
    const float* __restrict__ Qw, const float* __restrict__ Qb,
    const float* __restrict__ Kw, const float* __restrict__ Kb,
    const float* __restrict__ Vw, const float* __restrict__ Vb,
    unsigned short* __restrict__ Abf, unsigned short* __restrict__ Bbf,
    unsigned short* __restrict__ vT) {
  __shared__ float Ws[128 * 65];
  __shared__ float hs[64 * 65];
  const int t = threadIdx.x;
  const int r0 = blockIdx.x * 64;
  const int m = blockIdx.y;
  const float* W = (m == 0) ? Qw : (m == 1) ? Kw : Vw;
  const float* bias = (m == 0) ? Qb : (m == 1) ? Kb : Vb;

  const int c = t & 127;
  const int rh = t >> 7;
  float acc[32];
#pragma unroll
  for (int r = 0; r < 32; ++r) acc[r] = 0.f;

  for (int kk = 0; kk < 2; ++kk) {
    __syncthreads();
#pragma unroll
    for (int it = 0; it < 8; ++it) {
      int idx = it * 256 + t;
      int c2 = idx >> 4;
      int q = idx & 15;
      float4 v = ((const float4*)(W + (size_t)c2 * 128 + kk * 64))[q];
      Ws[c2 * 65 + q * 4 + 0] = v.x;
      Ws[c2 * 65 + q * 4 + 1] = v.y;
      Ws[c2 * 65 + q * 4 + 2] = v.z;
      Ws[c2 * 65 + q * 4 + 3] = v.w;
    }
#pragma unroll
    for (int it = 0; it < 4; ++it) {
      int idx = it * 256 + t;
      int r = idx >> 4;
      int q = idx & 15;
      float4 v = ((const float4*)(h + (size_t)(r0 + r) * 128 + kk * 64))[q];
      hs[r * 65 + q * 4 + 0] = v.x;
      hs[r * 65 + q * 4 + 1] = v.y;
      hs[r * 65 + q * 4 + 2] = v.z;
      hs[r * 65 + q * 4 + 3] = v.w;
    }
    __syncthreads();
    for (int k = 0; k < 64; ++k) {
      float wk = Ws[c * 65 + k];
#pragma unroll
      for (int r = 0; r < 32; ++r)
        acc[r] += hs[(rh * 32 + r) * 65 + k] * wk;
    }
  }

  float bv = bias[c];
  float scale = (m == 0) ? 0.08838834764831845f : 1.0f;  // 1/sqrt(128) folded into q
#pragma unroll
  for (int r = 0; r < 32; ++r) {
    int row = r0 + rh * 32 + r;
    unsigned short bf = f2bf((acc[r] + bv) * scale);
    if (m == 0)      Abf[(size_t)row * KDIM + 6144 + c] = bf;
    else if (m == 1) Bbf[(size_t)row * KDIM + 6144 + c] = bf;
    else             vT[(size_t)c * NN + row] = bf;
  }
}

// ---------------- fp32 -> bf16 conversion of e, Pw, Gw ----------------
__global__ __launch_bounds__(256) void convert_kernel(
    const float* __restrict__ e, const float* __restrict__ Pw, const float* __restrict__ Gw,
    unsigned short* __restrict__ Abf, unsigned short* __restrict__ Bbf) {
  const int row = blockIdx.x;
  const int which = blockIdx.y;
  const int t = threadIdx.x;
  const float* src;
  unsigned short* dst;
  if (which == 0)      { src = e  + (size_t)row * NN; dst = Abf + (size_t)row * KDIM; }
  else if (which == 1) { src = Pw + (size_t)row * NN; dst = Bbf + (size_t)row * KDIM; }
  else                 { src = Gw + (size_t)row * NN; dst = Bbf + (size_t)(row + NN) * KDIM; }
#pragma unroll
  for (int it = 0; it < 6; ++it) {
    int j4 = it * 256 + t;
    float4 v = ((const float4*)src)[j4];
    ushort4 p = make_ushort4(f2bf(v.x), f2bf(v.y), f2bf(v.z), f2bf(v.w));
    *(ushort4*)(dst + (size_t)j4 * 4) = p;
  }
  if (which == 2 && t < 32)   // zero the K-pad of the Gw rows
    *(ushort4*)(dst + 6144 + t * 4) = make_ushort4(0, 0, 0, 0);
}

// ---------------- small bf16 NT GEMM (m97 structure, kept for PV) ----------------
template <int ATOMIC>
__global__ __launch_bounds__(256) void gemm_nt(
    const unsigned short* __restrict__ A, const unsigned short* __restrict__ B,
    float* __restrict__ C, int lda, int ldb, int ldc, int kIters) {
  __shared__ short As[128 * 32];
  __shared__ short Bs[128 * 32];
  const int t = threadIdx.x;
  const int wave = t >> 6;
  const int lane = t & 63;
  const int rowBlk = blockIdx.y * 128;
  const int colBlk = blockIdx.x * 128;
  const int kStart = blockIdx.z * kIters * 32;
  const int wm = (wave >> 1) * 64;
  const int wn = (wave & 1) * 64;
  const int lm = lane & 15;
  const int quad = lane >> 4;

  f32x4 acc[4][4] = {};

  const char* Aab = (const char*)A + (size_t)kStart * 2;
  const char* Bab = (const char*)B + (size_t)kStart * 2;
  const size_t ldab = (size_t)lda * 2, ldbb = (size_t)ldb * 2;
  const int o0 = wave * 2048 + lane * 16;

  for (int kb = 0; kb < kIters; ++kb) {
    __syncthreads();
#pragma unroll
    for (int c = 0; c < 2; ++c) {
      int o = o0 + c * 1024;
      int r = o >> 6;
      int cb = o & 63;
      const char* ga = Aab + (size_t)(rowBlk + r) * ldab + (size_t)kb * 64 + cb;
      __builtin_amdgcn_global_load_lds(
          (const __attribute__((address_space(1))) unsigned int*)ga,
          (__attribute__((address_space(3))) unsigned int*)((char*)As + o), 16, 0, 0);
      const char* gb = Bab + (size_t)(colBlk + r) * ldbb + (size_t)kb * 64 + cb;
      __builtin_amdgcn_global_load_lds(
          (const __attribute__((address_space(1))) unsigned int*)gb,
          (__attribute__((address_space(3))) unsigned int*)((char*)Bs + o), 16, 0, 0);
    }
    __syncthreads();

    bf16x8 af[4], bfr[4];
#pragma unroll
    for (int mt = 0; mt < 4; ++mt)
      af[mt] = *(const bf16x8*)&As[(wm + mt * 16 + lm) * 32 + quad * 8];
#pragma unroll
    for (int nt = 0; nt < 4; ++nt)
      bfr[nt] = *(const bf16x8*)&Bs[(wn + nt * 16 + lm) * 32 + quad * 8];
#pragma unroll
    for (int mt = 0; mt < 4; ++mt)
#pragma unroll
      for (int nt = 0; nt < 4; ++nt)
        acc[mt][nt] = __builtin_amdgcn_mfma_f32_16x16x32_bf16(af[mt], bfr[nt], acc[mt][nt], 0, 0, 0);
  }

#pragma unroll
  for (int mt = 0; mt < 4; ++mt)
#pragma unroll
    for (int nt = 0; nt < 4; ++nt) {
      int col = colBlk + wn + nt * 16 + lm;
#pragma unroll
      for (int r = 0; r < 4; ++r) {
        int row = rowBlk + wm + mt * 16 + quad * 4 + r;
        if (ATOMIC) atomicAdd(&C[(size_t)row * ldc + col], acc[mt][nt][r]);
        else        C[(size_t)row * ldc + col] = acc[mt][nt][r];
      }
    }
}

// ---------------- 256x256 8-phase bf16 NT GEMM (m201-style template) ----------------
// BM=BN=256, BK=64, 8 waves (2Mx4N), 512 thr, 128KB LDS.
// C is written in BF16 (halves gemm write traffic + softmax read traffic;
// scores rounded post-fp32-accumulation, max-subtract cancels exactly).
// NOTE: XCD swizzle REVERTED (r4: doubled FETCH_SIZE, -3%). Default x-fast
// dispatch keeps a row-band working set that is L3-resident.
#define FENCE() asm volatile("" ::: "memory")
#define BAR() do { FENCE(); __builtin_amdgcn_sched_barrier(0); \
                   __builtin_amdgcn_s_barrier(); \
                   __builtin_amdgcn_sched_barrier(0); FENCE(); } while (0)
#define RDB(buf) do { \
  bR[0][0]=LDB_(buf,0,0); bR[1][0]=LDB_(buf,1,0); bR[2][0]=LDB_(buf,2,0); bR[3][0]=LDB_(buf,3,0); \
  bR[0][1]=LDB_(buf,0,1); bR[1][1]=LDB_(buf,1,1); bR[2][1]=LDB_(buf,2,1); bR[3][1]=LDB_(buf,3,1); } while (0)
#define RDA2(buf,m0,m1) do { \
  aR[m0][0]=LDA_(buf,m0,0); aR[m0][1]=LDA_(buf,m0,1); \
  aR[m1][0]=LDA_(buf,m1,0); aR[m1][1]=LDA_(buf,m1,1); } while (0)
#define MF(m,n,k) acc[m][n]=__builtin_amdgcn_mfma_f32_16x16x32_bf16(aR[m][k],bR[n][k],acc[m][n],0,0,0)
#define MFMA16(m0,m1) do { \
  MF(m0,0,0); MF(m0,1,0); MF(m0,2,0); MF(m0,3,0); \
  MF(m1,0,0); MF(m1,1,0); MF(m1,2,0); MF(m1,3,0); \
  MF(m0,0,1); MF(m0,1,1); MF(m0,2,1); MF(m0,3,1); \
  MF(m1,0,1); MF(m1,1,1); MF(m1,2,1); MF(m1,3,1); } while (0)

__global__ __launch_bounds__(512, 2) void gemm256(
    const unsigned short* __restrict__ A, const unsigned short* __restrict__ B,
    unsigned short* __restrict__ C) {
  __shared__ short As[2][256 * 64];
  __shared__ short Bs[2][256 * 64];
  const int t = threadIdx.x;
  const int wave = t >> 6;
  const int lane = t & 63;
  const int wm = wave >> 2;            // 0..1  (M wave row)
  const int wn = wave & 3;             // 0..3  (N wave col)
  const int lm = lane & 15;
  const int quad = lane >> 4;
  const int rowBlk = blockIdx.y * 256;
  const int colBlk = blockIdx.x * 256;

  const int sRow = wave * 8 + (lane >> 3);                  // staging row in 64-row group
  const int sCol = ((lane & 7) ^ ((lane >> 3) & 7)) * 16;   // pre-swizzled byte col (T2)
  const int sLds = wave * 1024 + lane * 16;                 // linear LDS dest

  f32x4 acc[8][4] = {};
  bf16x8 aR[8][2], bR[4][2];

  auto STAGE = [&](short* lds, const unsigned short* g, int gr0, int tile, int half) {
#pragma unroll
    for (int j = 0; j < 2; ++j) {
      const char* ga = (const char*)g +
          (size_t)(gr0 + half * 128 + j * 64 + sRow) * (size_t)(KDIM * 2) +
          (size_t)tile * 128 + sCol;
      char* la = (char*)lds + half * 16384 + j * 8192 + sLds;
      __builtin_amdgcn_global_load_lds(
          (const __attribute__((address_space(1))) unsigned int*)ga,
          (__attribute__((address_space(3))) unsigned int*)la, 16, 0, 0);
    }
  };
  auto LDA_ = [&](int buf, int mt, int ks) -> bf16x8 {
    int r = wm * 128 + mt * 16 + lm;
    int pc = ((ks * 4 + quad) ^ (lm & 7)) * 16;
    return *(const bf16x8*)((const char*)As[buf] + r * 128 + pc);
  };
  auto LDB_ = [&](int buf, int nt, int ks) -> bf16x8 {
    int r = wn * 64 + nt * 16 + lm;
    int pc = ((ks * 4 + quad) ^ (lm & 7)) * 16;
    return *(const bf16x8*)((const char*)Bs[buf] + r * 128 + pc);
  };

  // prologue: tile0 (A h0,h1, B h0,h1) + tile1 (B h0,h1, A h0) = 7 half-tiles
  STAGE(As[0], A, rowBlk, 0, 0);
  STAGE(As[0], A, rowBlk, 0, 1);
  STAGE(Bs[0], B, colBlk, 0, 0);
  STAGE(Bs[0], B, colBlk, 0, 1);
  STAGE(Bs[1], B, colBlk, 1, 0);
  STAGE(Bs[1], B, colBlk, 1, 1);
  STAGE(As[1], A, rowBlk, 1, 0);
  asm volatile("s_waitcnt vmcnt(6)" ::: "memory");   // tile0 landed
  BAR();

  for (int tk = 0; tk < NTILE; tk += 2) {
    const bool g2 = (tk + 2) < NTILE;
    const bool g3 = (tk + 3) < NTILE;
    // ---- ph1: tile tk (buf0), mt 0,1 ----
    STAGE(As[1], A, rowBlk, tk + 1, 1);              // A h1 of tile tk+1
    RDB(0); RDA2(0, 0, 1);
    asm volatile("s_waitcnt lgkmcnt(8)" ::: "memory");
    BAR();
    __builtin_amdgcn_s_setprio(1); MFMA16(0, 1); __builtin_amdgcn_s_setprio(0);
    BAR();
    // ---- ph2: mt 2,3 ----
    if (g2) STAGE(Bs[0], B, colBlk, tk + 2, 0);
    RDA2(0, 2, 3); RDA2(0, 4, 5);
    BAR();
    __builtin_amdgcn_s_setprio(1); MFMA16(2, 3); __builtin_amdgcn_s_setprio(0);
    BAR();
    // ---- ph3: mt 4,5 ----
    if (g2) STAGE(Bs[0], B, colBlk, tk + 2, 1);
    RDA2(0, 6, 7);
    BAR();
    __builtin_amdgcn_s_setprio(1); MFMA16(4, 5); __builtin_amdgcn_s_setprio(0);
    BAR();
    // ---- ph4: mt 6,7; drain so tile tk+1 is fully present ----
    if (g2) STAGE(As[0], A, rowBlk, tk + 2, 0);
    BAR();
    __builtin_amdgcn_s_setprio(1); MFMA16(6, 7); __builtin_amdgcn_s_setprio(0);
    if (g2) { asm volatile("s_waitcnt vmcnt(6)" ::: "memory"); }
    else    { asm volatile("s_waitcnt vmcnt(0)" ::: "memory"); }
    BAR();
    // ---- ph5: tile tk+1 (buf1), mt 0,1 ----
    if (g2) STAGE(As[0], A, rowBlk, tk + 2, 1);
    RDB(1); RDA2(1, 0, 1);
    asm volatile("s_waitcnt lgkmcnt(8)" ::: "memory");
    BAR();
    __builtin_amdgcn_s_setprio(1); MFMA16(0, 1); __builtin_amdgcn_s_setprio(0);
    BAR();
    // ---- ph6: mt 2,3 ----
    if (g3) STAGE(Bs[1], B, colBlk, tk + 3, 0);
    RDA2(1, 2, 3); RDA2(1, 4, 5);
    BAR();
    __builtin_amdgcn_s_setprio(1); MFMA16(2, 3); __builtin_amdgcn_s_setprio(0);
    BAR();
    // ---- ph7: mt 4,5 ----
    if (g3) STAGE(Bs[1], B, colBlk, tk + 3, 1);
    RDA2(1, 6, 7);
    BAR();
    __builtin_amdgcn_s_setprio(1); MFMA16(4, 5); __builtin_amdgcn_s_setprio(0);
    BAR();
    // ---- ph8: mt 6,7; drain so tile tk+2 is fully present ----
    if (g3) STAGE(As[1], A, rowBlk, tk + 3, 0);
    BAR();
    __builtin_amdgcn_s_setprio(1); MFMA16(6, 7); __builtin_amdgcn_s_setprio(0);
    if (g3) { asm volatile("s_waitcnt vmcnt(6)" ::: "memory"); }
    else    { asm volatile("s_waitcnt vmcnt(0)" ::: "memory"); }
    BAR();
  }

  // ---- C write (bf16) ----
#pragma unroll
  for (int mt = 0; mt < 8; ++mt)
#pragma unroll
    for (int nt = 0; nt < 4; ++nt) {
      int col = colBlk + wn * 64 + nt * 16 + lm;
#pragma unroll
      for (int r = 0; r < 4; ++r) {
        int row = rowBlk + wm * 128 + mt * 16 + quad * 4 + r;
        C[(size_t)row * NB + col] = f2bf(acc[mt][nt][r]);
      }
    }
}

// ---------------- JAX Threefry-2x32-20, key(42) = (0, 42) ----------------
static __device__ __forceinline__ void threefry(uint32_t& x0, uint32_t& x1) {
  const uint32_t ks0 = 0u, ks1 = 42u, ks2 = 0u ^ 42u ^ 0x1BD11BDAu;
  x0 += ks0; x1 += ks1;
#define TFR(r) { x0 += x1; x1 = (x1 << (r)) | (x1 >> (32 - (r))); x1 ^= x0; }
  TFR(13) TFR(15) TFR(26) TFR(6)
  x0 += ks1; x1 += ks2 + 1u;
  TFR(17) TFR(29) TFR(16) TFR(24)
  x0 += ks2; x1 += ks0 + 2u;
  TFR(13) TFR(15) TFR(26) TFR(6)
  x0 += ks0; x1 += ks1 + 3u;
  TFR(17) TFR(29) TFR(16) TFR(24)
  x0 += ks1; x1 += ks2 + 4u;
  TFR(13) TFR(15) TFR(26) TFR(6)
  x0 += ks2; x1 += ks0 + 5u;
#undef TFR
}

// Partitionable threefry (JAX default), x32 mode: counter (0, i);
// bits = y0 ^ y1; u = bitcast((bits>>9)|0x3F800000) - 1.0f; keep = u < 0.8f
static __device__ __forceinline__ int keep32p(uint32_t idx) {
  uint32_t x0 = 0u, x1 = idx;
  threefry(x0, x1);
  uint32_t bits = x0 ^ x1;
  float u = __uint_as_float((bits >> 9) | 0x3F800000u) - 1.0f;
  return u < 0.8f;
}

// ---------------- softmax + bias + sigmoid-gate + dropout (bf16 C input) ----------------
__global__ __launch_bounds__(256) void softmax_gate(
    const unsigned short* __restrict__ C,
    const float* __restrict__ Pb, const float* __restrict__ Gb,
    unsigned short* __restrict__ attw) {
  __shared__ float srow[NN];
  __shared__ float red[4];
  const int t = threadIdx.x;
  const int wave = t >> 6, lane = t & 63;
  const int i = blockIdx.x;

  float mx = -1e30f;
  const ushort4* src = (const ushort4*)(C + (size_t)i * NB);
  const float4* pb4 = (const float4*)Pb;
#pragma unroll
  for (int it = 0; it < 6; ++it) {
    int j4 = it * 256 + t;
    ushort4 sv = src[j4];
    float4 p = pb4[j4];
    float4 v;
    v.x = bf2f(sv.x) + p.x; v.y = bf2f(sv.y) + p.y;
    v.z = bf2f(sv.z) + p.z; v.w = bf2f(sv.w) + p.w;
    ((float4*)srow)[j4] = v;
    mx = fmaxf(mx, fmaxf(fmaxf(v.x, v.y), fmaxf(v.z, v.w)));
  }
  for (int off = 32; off > 0; off >>= 1) mx = fmaxf(mx, __shfl_xor(mx, off, 64));
  if (lane == 0) red[wave] = mx;
  __syncthreads();
  const float M = fmaxf(fmaxf(red[0], red[1]), fmaxf(red[2], red[3]));
  __syncthreads();

  float sm = 0.f;
#pragma unroll
  for (int it = 0; it < 6; ++it) {
    int j4 = it * 256 + t;
    float4 v = ((float4*)srow)[j4];
    v.x = __expf(v.x - M); v.y = __expf(v.y - M);
    v.z = __expf(v.z - M); v.w = __expf(v.w - M);
    ((float4*)srow)[j4] = v;
    sm += v.x + v.y + v.z + v.w;
  }
  for (int off = 32; off > 0; off >>= 1) sm += __shfl_xor(sm, off, 64);
  if (lane == 0) red[wave] = sm;
  __syncthreads();
  const float inv = 1.25f / (red[0] + red[1] + red[2] + red[3]);  // 1/(0.8*sum)

  const ushort4* gp  = (const ushort4*)(C + (size_t)i * NB + 6144);
  const float4* gb4 = (const float4*)Gb;
  const uint32_t base = (uint32_t)i * (uint32_t)NN;
  for (int it = 0; it < 6; ++it) {
    int j4 = it * 256 + t;
    int j = j4 * 4;
    ushort4 gl = gp[j4];
    float4 gb = gb4[j4];
    float4 pv = ((float4*)srow)[j4];
    float a[4]  = { bf2f(gl.x), bf2f(gl.y), bf2f(gl.z), bf2f(gl.w) };
    float ab[4] = { gb.x, gb.y, gb.z, gb.w };
    float ev[4] = { pv.x, pv.y, pv.z, pv.w };
    unsigned short w[4];
#pragma unroll
    for (int u = 0; u < 4; ++u) {
      int kp = keep32p(base + (uint32_t)(j + u));
      float s = 1.f / (1.f + __expf(-(a[u] + ab[u])));
      float val = kp ? s * ev[u] * inv : 0.f;
      w[u] = f2bf(val);
    }
    *(ushort4*)(attw + (size_t)i * NN + j) = make_ushort4(w[0], w[1], w[2], w[3]);
  }
}

// ---------------- launch ----------------
extern "C" void kernel_launch(void* const* d_in, const int* in_sizes, int n_in,
                              void* d_out, int out_size, void* d_ws, size_t ws_size,
                              hipStream_t stream) {
  (void)in_sizes; (void)n_in; (void)out_size; (void)ws_size;
  const float* h  = (const float*)d_in[0];
  const float* e  = (const float*)d_in[1];
  const float* Qw = (const float*)d_in[2];
  const float* Qb = (const float*)d_in[3];
  const float* Kw = (const float*)d_in[4];
  const float* Kb = (const float*)d_in[5];
  const float* Vw = (const float*)d_in[6];
  const float* Vb = (const float*)d_in[7];
  const float* Pw = (const float*)d_in[8];
  const float* Pb = (const float*)d_in[9];
  const float* Gw = (const float*)d_in[10];
  const float* Gb = (const float*)d_in[11];
  float* out = (float*)d_out;

  char* ws = (char*)d_ws;
  unsigned short* Abf  = (unsigned short*)(ws);                       // [6144][6272] bf16: [e | q/sqrt(d)]
  unsigned short* Bbf  = (unsigned short*)(ws + 77070336ull);         // [12288][6272] bf16: [[Pw|k],[Gw|0]]
  unsigned short* Cbuf = (unsigned short*)(ws + 231211008ull);        // [6144][12288] bf16 scores|gate
  unsigned short* vT   = (unsigned short*)(ws + 533348352ull);        // [128][6144] bf16
  unsigned short* attw = Abf;  // alias: A' dead after big GEMM

  zero_kernel<<<768, 256, 0, stream>>>(out, 196608);
  qkv_proj<<<dim3(96, 3), 256, 0, stream>>>(h, Qw, Qb, Kw, Kb, Vw, Vb, Abf, Bbf, vT);
  convert_kernel<<<dim3(6144, 3), 256, 0, stream>>>(e, Pw, Gw, Abf, Bbf);
  gemm256<<<dim3(48, 24), 512, 0, stream>>>(Abf, Bbf, Cbuf);
  softmax_gate<<<6144, 256, 0, stream>>>(Cbuf, Pb, Gb, attw);
  gemm_nt<1><<<dim3(1, 48, 4), 256, 0, stream>>>(attw, vT, out, NN, NN, 128, 48);
}